// Round 1
// baseline (571.059 us; speedup 1.0000x reference)
//
#include <hip/hip_runtime.h>
#include <hip/hip_bf16.h>

// GNNLayer (GatedGCN-ish): B=8, N=200, D=128, fp32 I/O.
// Strategy: recompute-Ce two-pass. K1: e->Ce (bf16 MFMA) -> e_new -> sigmoid
// -> agg + BN partial sums (no big intermediate store). K4: recompute Ce,
// apply BN+relu+residual, write e_out. HBM floor ~492 MB.

#define B_ 8
#define N_ 200
#define D_ 128
#define BN_ (B_*N_)      // 1600
#define HN_ (BN_*D_)     // 204800 floats per [B,N,D] tensor
#define EN_ (BN_*N_*D_)  // 40960000 floats in e

typedef __attribute__((ext_vector_type(8))) short short8v;
typedef __attribute__((ext_vector_type(4))) short short4v;
typedef __attribute__((ext_vector_type(4))) float float4v;
typedef __attribute__((ext_vector_type(4))) unsigned int uint4v;

__device__ __forceinline__ unsigned short f2b(float f) {
  // float -> bf16 bits, round-to-nearest-even
  unsigned u = __float_as_uint(f);
  u += 0x7FFFu + ((u >> 16) & 1u);
  return (unsigned short)(u >> 16);
}

// ---------------------------------------------------------------------------
// K0: Uh/Vh/Ah/Bh = h @ {U,V,A,B}w.T + bias  (fp32, small: 1600x128 each)
//     blocks 100..115 convert Cw (128x128 fp32) -> bf16 bits in ws.
// ---------------------------------------------------------------------------
__global__ __launch_bounds__(256) void prelin_kernel(
    const float* __restrict__ h,
    const float* __restrict__ Uw, const float* __restrict__ Ub,
    const float* __restrict__ Vw, const float* __restrict__ Vb,
    const float* __restrict__ Aw, const float* __restrict__ Ab,
    const float* __restrict__ Bw, const float* __restrict__ Bb,
    const float* __restrict__ Cw,
    float* __restrict__ Uh, float* __restrict__ Vh,
    float* __restrict__ Ah, float* __restrict__ Bh,
    unsigned short* __restrict__ Cwbf) {
  const int tid = threadIdx.x;
  if (blockIdx.x >= 100) {                      // Cw -> bf16 (16 blocks)
    int g = (blockIdx.x - 100) * 1024 + tid * 4;
    float4v v = *(const float4v*)(Cw + g);
    short4v s;
    s.x = (short)f2b(v.x); s.y = (short)f2b(v.y);
    s.z = (short)f2b(v.z); s.w = (short)f2b(v.w);
    *(short4v*)(Cwbf + g) = s;
    return;
  }
  const int r0 = blockIdx.x * 16;               // 16 h-rows per block
  __shared__ float hs[16][128];
  for (int k = 0; k < 2; k++) {
    int g = k * 256 + tid;                      // 512 float4 chunks
    int row = g >> 5, col4 = g & 31;
    *(float4v*)&hs[row][col4 * 4] =
        *(const float4v*)(h + (size_t)(r0 + row) * D_ + col4 * 4);
  }
  __syncthreads();
  // thread computes output cols (c0 = tid, c1 = tid+256) of 512-wide [U|V|A|B]
  const int c0 = tid, c1 = tid + 256;
  const float* w0 = (c0 < 128) ? (Uw + c0 * 128) : (Vw + (c0 - 128) * 128);
  const float  b0 = (c0 < 128) ? Ub[c0] : Vb[c0 - 128];
  const float* w1 = (c1 < 384) ? (Aw + (c1 - 256) * 128) : (Bw + (c1 - 384) * 128);
  const float  b1 = (c1 < 384) ? Ab[c1 - 256] : Bb[c1 - 384];
  float acc0[16], acc1[16];
#pragma unroll
  for (int r = 0; r < 16; r++) { acc0[r] = 0.f; acc1[r] = 0.f; }
  for (int k = 0; k < 128; k += 4) {
    float4v w0v = *(const float4v*)(w0 + k);
    float4v w1v = *(const float4v*)(w1 + k);
#pragma unroll
    for (int r = 0; r < 16; r++) {
      float4v hv = *(const float4v*)&hs[r][k];   // wave-broadcast read
      acc0[r] = fmaf(hv.x, w0v.x, fmaf(hv.y, w0v.y, fmaf(hv.z, w0v.z, fmaf(hv.w, w0v.w, acc0[r]))));
      acc1[r] = fmaf(hv.x, w1v.x, fmaf(hv.y, w1v.y, fmaf(hv.z, w1v.z, fmaf(hv.w, w1v.w, acc1[r]))));
    }
  }
  float* dst0 = (c0 < 128) ? Uh : Vh; const int cc0 = c0 & 127;
  float* dst1 = (c1 < 384) ? Ah : Bh; const int cc1 = (c1 - 256) & 127;
#pragma unroll
  for (int r = 0; r < 16; r++) {
    dst0[(size_t)(r0 + r) * D_ + cc0] = acc0[r] + b0;
    dst1[(size_t)(r0 + r) * D_ + cc1] = acc1[r] + b1;
  }
}

// ---------------------------------------------------------------------------
// K1/K4: per-(b,i) block. GEMM e_tile[64x128] @ Cw^T via mfma 16x16x32 bf16.
// MODE 0: e_new -> sigmoid -> agg over j, BN partial sums.
// MODE 1: e_new -> BN scale/shift -> relu -> + e_in -> e_out.
// ---------------------------------------------------------------------------
template <int MODE>
__global__ __launch_bounds__(256, 2) void gemm_pass(
    const float* __restrict__ e, const unsigned short* __restrict__ Cwbf,
    const float* __restrict__ Cb, const float* __restrict__ Ah,
    const float* __restrict__ Bh, const float* __restrict__ Vh,
    float* __restrict__ agg, float* __restrict__ psum, float* __restrict__ psumsq,
    const float* __restrict__ scale_e, const float* __restrict__ shift_e,
    float* __restrict__ e_out) {
  const int tid = threadIdx.x;
  const int blk = blockIdx.x;            // (b,i)
  const int b = blk / N_;
  const int lane = tid & 63, wz = tid >> 6;
  const int c = lane & 15, q = lane >> 4;

  // LDS: strides padded so word-stride mod 32 == 4 (<=2-way conflicts, free)
  __shared__ __align__(16) unsigned short Bs[128 * 136];  // Cw bf16 [n][k]
  __shared__ __align__(16) unsigned short As[64 * 136];   // e tile bf16 [j][k]
  __shared__ float base_s[128];                           // Cb + Bh[b,i,:]
  __shared__ float ss_s[256];                             // MODE1 scale|shift

  // stage Cw (bf16, pre-converted) into Bs
  const uint4v* bsrc = (const uint4v*)Cwbf;
#pragma unroll
  for (int k2 = 0; k2 < 8; k2++) {
    int g = k2 * 256 + tid;              // 2048 chunks of 8 shorts
    int row = g >> 4, col = (g & 15) * 8;
    *(uint4v*)&Bs[row * 136 + col] = bsrc[g];
  }
  if (tid < 128) {
    base_s[tid] = Cb[tid] + Bh[(size_t)blk * D_ + tid];
    if (MODE == 1) { ss_s[tid] = scale_e[tid]; ss_s[128 + tid] = shift_e[tid]; }
  }

  float aggv[8], sumv[8], sqv[8];
  if (MODE == 0) {
#pragma unroll
    for (int t = 0; t < 8; t++) { aggv[t] = 0.f; sumv[t] = 0.f; sqv[t] = 0.f; }
  }

  const float* erow = e + (size_t)blk * N_ * D_;     // e[b,i,:,:]
  const float* AhB = Ah + (size_t)b * N_ * D_;
  const float* VhB = (MODE == 0) ? (Vh + (size_t)b * N_ * D_) : nullptr;

  for (int jt = 0; jt < 4; jt++) {
    const int j0 = jt * 64;
    __syncthreads();
    // stage 64 e-rows -> bf16 LDS (zero-fill rows >= N)
#pragma unroll
    for (int k2 = 0; k2 < 8; k2++) {
      int g = k2 * 256 + tid;            // 2048 float4 chunks
      int row = g >> 5, col4 = g & 31;
      int j = j0 + row;
      float4v v;
      if (j < N_) v = *(const float4v*)(erow + (size_t)j * D_ + col4 * 4);
      else        v = (float4v){0.f, 0.f, 0.f, 0.f};
      short4v sv;
      sv.x = (short)f2b(v.x); sv.y = (short)f2b(v.y);
      sv.z = (short)f2b(v.z); sv.w = (short)f2b(v.w);
      *(short4v*)&As[row * 136 + col4 * 4] = sv;
    }
    __syncthreads();

    float4v acc[8];
#pragma unroll
    for (int t = 0; t < 8; t++) acc[t] = (float4v){0.f, 0.f, 0.f, 0.f};
    const unsigned short* arow = &As[(wz * 16 + c) * 136];
    const int ko = q * 8;
#pragma unroll
    for (int kk = 0; kk < 128; kk += 32) {
      short8v av = *(const short8v*)(arow + kk + ko);
#pragma unroll
      for (int t = 0; t < 8; t++) {
        short8v bv = *(const short8v*)&Bs[(t * 16 + c) * 136 + kk + ko];
        acc[t] = __builtin_amdgcn_mfma_f32_16x16x32_bf16(av, bv, acc[t], 0, 0, 0);
      }
    }

    // epilogue: D layout col = lane&15, row = q*4 + reg (m89-verified)
#pragma unroll
    for (int t = 0; t < 8; t++) {
      const int n = t * 16 + c;
      const float bse = base_s[n];
      float sc = 0.f, sh = 0.f;
      if (MODE == 1) { sc = ss_s[n]; sh = ss_s[128 + n]; }
#pragma unroll
      for (int r = 0; r < 4; r++) {
        const int j = j0 + wz * 16 + q * 4 + r;
        if (j < N_) {
          float x = acc[t][r] + bse + AhB[(size_t)j * D_ + n];
          if (MODE == 0) {
            float g = __builtin_amdgcn_rcpf(1.0f + __expf(-x));
            aggv[t] += g * VhB[(size_t)j * D_ + n];
            sumv[t] += x;
            sqv[t] += x * x;
          } else {
            float y = fmaxf(x * sc + sh, 0.f);
            size_t idx = (size_t)blk * N_ * D_ + (size_t)j * D_ + n;
            e_out[idx] = e[idx] + y;   // residual (re-read is L2-hot)
          }
        }
      }
    }
  }

  if (MODE == 0) {
    __syncthreads();                    // all MFMA reads of As done
    float* red = (float*)As;            // reuse A-tile LDS: [3][4][128]
#pragma unroll
    for (int t = 0; t < 8; t++) {
      float a = aggv[t], s = sumv[t], sq = sqv[t];
      a += __shfl_xor(a, 16); a += __shfl_xor(a, 32);
      s += __shfl_xor(s, 16); s += __shfl_xor(s, 32);
      sq += __shfl_xor(sq, 16); sq += __shfl_xor(sq, 32);
      if (q == 0) {
        red[(0 * 4 + wz) * 128 + t * 16 + c] = a;
        red[(1 * 4 + wz) * 128 + t * 16 + c] = s;
        red[(2 * 4 + wz) * 128 + t * 16 + c] = sq;
      }
    }
    __syncthreads();
    if (tid < 128) {
      float a = 0.f, s = 0.f, sq = 0.f;
#pragma unroll
      for (int w = 0; w < 4; w++) {
        a += red[(0 * 4 + w) * 128 + tid];
        s += red[(1 * 4 + w) * 128 + tid];
        sq += red[(2 * 4 + w) * 128 + tid];
      }
      agg[(size_t)blk * D_ + tid] = a;
      psum[(size_t)blk * D_ + tid] = s;
      psumsq[(size_t)blk * D_ + tid] = sq;
    }
  }
}

// ---------------------------------------------------------------------------
// K2: reduce BN partials -> scale/shift for e and h (128 blocks, 1/channel)
// ---------------------------------------------------------------------------
__global__ __launch_bounds__(256) void stats_kernel(
    const float* __restrict__ psum, const float* __restrict__ psumsq,
    const float* __restrict__ Uh, const float* __restrict__ agg,
    const float* __restrict__ gamma_h, const float* __restrict__ beta_h,
    const float* __restrict__ gamma_e, const float* __restrict__ beta_e,
    float* __restrict__ scale_e, float* __restrict__ shift_e,
    float* __restrict__ scale_h, float* __restrict__ shift_h) {
  const int n = blockIdx.x, t = threadIdx.x;
  float s = 0.f, sq = 0.f, hs = 0.f, hsq = 0.f;
  for (int k = t; k < BN_; k += 256) {
    s += psum[(size_t)k * D_ + n];
    sq += psumsq[(size_t)k * D_ + n];
    float hv = Uh[(size_t)k * D_ + n] + agg[(size_t)k * D_ + n];
    hs += hv; hsq += hv * hv;
  }
  __shared__ float r4[4][256];
  r4[0][t] = s; r4[1][t] = sq; r4[2][t] = hs; r4[3][t] = hsq;
  __syncthreads();
  for (int off = 128; off > 0; off >>= 1) {
    if (t < off) {
      r4[0][t] += r4[0][t + off]; r4[1][t] += r4[1][t + off];
      r4[2][t] += r4[2][t + off]; r4[3][t] += r4[3][t + off];
    }
    __syncthreads();
  }
  if (t == 0) {
    const float Me = (float)(B_ * N_ * N_);
    float mean = r4[0][0] / Me;
    float var = r4[1][0] / Me - mean * mean;
    float sce = gamma_e[n] * rsqrtf(var + 1e-5f);
    scale_e[n] = sce; shift_e[n] = beta_e[n] - mean * sce;
    const float Mh = (float)BN_;
    float mh = r4[2][0] / Mh;
    float vh = r4[3][0] / Mh - mh * mh;
    float sch = gamma_h[n] * rsqrtf(vh + 1e-5f);
    scale_h[n] = sch; shift_h[n] = beta_h[n] - mh * sch;
  }
}

// ---------------------------------------------------------------------------
// K3h: h_out = h + relu((Uh+agg)*scale_h + shift_h)   (tiny)
// ---------------------------------------------------------------------------
__global__ __launch_bounds__(256) void hpath_kernel(
    const float* __restrict__ h, const float* __restrict__ Uh,
    const float* __restrict__ agg, const float* __restrict__ scale_h,
    const float* __restrict__ shift_h, float* __restrict__ h_out) {
  const int idx = blockIdx.x * 256 + threadIdx.x;   // float4 index, 51200
  float4v u = ((const float4v*)Uh)[idx];
  float4v a = ((const float4v*)agg)[idx];
  float4v hv = ((const float4v*)h)[idx];
  float4v sc = ((const float4v*)scale_h)[idx & 31];
  float4v sh = ((const float4v*)shift_h)[idx & 31];
  float4v o;
#pragma unroll
  for (int l = 0; l < 4; l++) {
    float y = fmaxf((u[l] + a[l]) * sc[l] + sh[l], 0.f);
    o[l] = hv[l] + y;
  }
  ((float4v*)h_out)[idx] = o;
}

// ---------------------------------------------------------------------------
extern "C" void kernel_launch(void* const* d_in, const int* in_sizes, int n_in,
                              void* d_out, int out_size, void* d_ws, size_t ws_size,
                              hipStream_t stream) {
  const float* h  = (const float*)d_in[0];
  const float* e  = (const float*)d_in[1];
  const float* Uw = (const float*)d_in[2];  const float* Ub = (const float*)d_in[3];
  const float* Vw = (const float*)d_in[4];  const float* Vb = (const float*)d_in[5];
  const float* Aw = (const float*)d_in[6];  const float* Ab = (const float*)d_in[7];
  const float* Bw = (const float*)d_in[8];  const float* Bb = (const float*)d_in[9];
  const float* Cw = (const float*)d_in[10]; const float* Cb = (const float*)d_in[11];
  const float* gamma_h = (const float*)d_in[12]; const float* beta_h = (const float*)d_in[13];
  const float* gamma_e = (const float*)d_in[14]; const float* beta_e = (const float*)d_in[15];

  float* ws = (float*)d_ws;
  float* Uh = ws + 0;
  float* Vh = ws + (size_t)HN_;
  float* Ah = ws + (size_t)HN_ * 2;
  float* Bh = ws + (size_t)HN_ * 3;
  float* agg = ws + (size_t)HN_ * 4;
  float* psum = ws + (size_t)HN_ * 5;
  float* psumsq = ws + (size_t)HN_ * 6;
  float* scale_e = ws + (size_t)HN_ * 7;
  float* shift_e = scale_e + 128;
  float* scale_h = scale_e + 256;
  float* shift_h = scale_e + 384;
  unsigned short* Cwbf = (unsigned short*)(scale_e + 512);

  float* h_out = (float*)d_out;
  float* e_out = (float*)d_out + HN_;

  prelin_kernel<<<116, 256, 0, stream>>>(h, Uw, Ub, Vw, Vb, Aw, Ab, Bw, Bb, Cw,
                                         Uh, Vh, Ah, Bh, Cwbf);
  gemm_pass<0><<<BN_, 256, 0, stream>>>(e, Cwbf, Cb, Ah, Bh, Vh,
                                        agg, psum, psumsq,
                                        nullptr, nullptr, nullptr);
  stats_kernel<<<128, 256, 0, stream>>>(psum, psumsq, Uh, agg,
                                        gamma_h, beta_h, gamma_e, beta_e,
                                        scale_e, shift_e, scale_h, shift_h);
  hpath_kernel<<<200, 256, 0, stream>>>(h, Uh, agg, scale_h, shift_h, h_out);
  gemm_pass<1><<<BN_, 256, 0, stream>>>(e, Cwbf, Cb, Ah, Bh, nullptr,
                                        nullptr, nullptr, nullptr,
                                        scale_e, shift_e, e_out);
}

// Round 2
// 484.679 us; speedup vs baseline: 1.1782x; 1.1782x over previous
//
#include <hip/hip_runtime.h>
#include <hip/hip_bf16.h>

// GNNLayer: B=8, N=200, D=128, fp32 I/O. Recompute-Ce two-pass, bf16 MFMA.
// R2: barrier-free K-loop (direct global->register e-fragments, Cw-only LDS),
// MODE1 operand-swapped for float4 epilogue, coalesced two-stage BN stats.

#define B_ 8
#define N_ 200
#define D_ 128
#define BN_ (B_*N_)      // 1600
#define HN_ (BN_*D_)     // 204800

typedef __attribute__((ext_vector_type(8))) short short8v;
typedef __attribute__((ext_vector_type(4))) short short4v;
typedef __attribute__((ext_vector_type(4))) float float4v;
typedef __attribute__((ext_vector_type(4))) unsigned int uint4v;

__device__ __forceinline__ unsigned short f2b(float f) {
  unsigned u = __float_as_uint(f);
  u += 0x7FFFu + ((u >> 16) & 1u);
  return (unsigned short)(u >> 16);
}

// ---------------------------------------------------------------------------
// K0: Uh/Vh/Ah/Bh = h @ {U,V,A,B}w.T + bias; blocks 100..115 convert Cw->bf16
// ---------------------------------------------------------------------------
__global__ __launch_bounds__(256) void prelin_kernel(
    const float* __restrict__ h,
    const float* __restrict__ Uw, const float* __restrict__ Ub,
    const float* __restrict__ Vw, const float* __restrict__ Vb,
    const float* __restrict__ Aw, const float* __restrict__ Ab,
    const float* __restrict__ Bw, const float* __restrict__ Bb,
    const float* __restrict__ Cw,
    float* __restrict__ Uh, float* __restrict__ Vh,
    float* __restrict__ Ah, float* __restrict__ Bh,
    unsigned short* __restrict__ Cwbf) {
  const int tid = threadIdx.x;
  if (blockIdx.x >= 100) {
    int g = (blockIdx.x - 100) * 1024 + tid * 4;
    float4v v = *(const float4v*)(Cw + g);
    short4v s;
    s.x = (short)f2b(v.x); s.y = (short)f2b(v.y);
    s.z = (short)f2b(v.z); s.w = (short)f2b(v.w);
    *(short4v*)(Cwbf + g) = s;
    return;
  }
  const int r0 = blockIdx.x * 16;
  __shared__ float hs[16][128];
  for (int k = 0; k < 2; k++) {
    int g = k * 256 + tid;
    int row = g >> 5, col4 = g & 31;
    *(float4v*)&hs[row][col4 * 4] =
        *(const float4v*)(h + (size_t)(r0 + row) * D_ + col4 * 4);
  }
  __syncthreads();
  const int c0 = tid, c1 = tid + 256;
  const float* w0 = (c0 < 128) ? (Uw + c0 * 128) : (Vw + (c0 - 128) * 128);
  const float  b0 = (c0 < 128) ? Ub[c0] : Vb[c0 - 128];
  const float* w1 = (c1 < 384) ? (Aw + (c1 - 256) * 128) : (Bw + (c1 - 384) * 128);
  const float  b1 = (c1 < 384) ? Ab[c1 - 256] : Bb[c1 - 384];
  float acc0[16], acc1[16];
#pragma unroll
  for (int r = 0; r < 16; r++) { acc0[r] = 0.f; acc1[r] = 0.f; }
  for (int k = 0; k < 128; k += 4) {
    float4v w0v = *(const float4v*)(w0 + k);
    float4v w1v = *(const float4v*)(w1 + k);
#pragma unroll
    for (int r = 0; r < 16; r++) {
      float4v hv = *(const float4v*)&hs[r][k];
      acc0[r] = fmaf(hv.x, w0v.x, fmaf(hv.y, w0v.y, fmaf(hv.z, w0v.z, fmaf(hv.w, w0v.w, acc0[r]))));
      acc1[r] = fmaf(hv.x, w1v.x, fmaf(hv.y, w1v.y, fmaf(hv.z, w1v.z, fmaf(hv.w, w1v.w, acc1[r]))));
    }
  }
  float* dst0 = (c0 < 128) ? Uh : Vh; const int cc0 = c0 & 127;
  float* dst1 = (c1 < 384) ? Ah : Bh; const int cc1 = (c1 - 256) & 127;
#pragma unroll
  for (int r = 0; r < 16; r++) {
    dst0[(size_t)(r0 + r) * D_ + cc0] = acc0[r] + b0;
    dst1[(size_t)(r0 + r) * D_ + cc1] = acc1[r] + b1;
  }
}

// ---------------------------------------------------------------------------
// K1/K4: per-(b,i) block, barrier-free K-loop.
// e-fragments: direct global->register (lane owns row j0+wz*16+c, cols q*8+..).
// MODE 0: D = e.Cw^T (lane: j=q*4+r rows, n=t*16+c). sigmoid-gate agg + BN sums.
// MODE 1: D = Cw.e^T (lane: j=c fixed, n=t*16+q*4+r). float4 epilogue + store.
// ---------------------------------------------------------------------------
template <int MODE>
__global__ __launch_bounds__(256, 2) void gemm_pass(
    const float* __restrict__ e, const unsigned short* __restrict__ Cwbf,
    const float* __restrict__ Cb, const float* __restrict__ Ah,
    const float* __restrict__ Bh, const float* __restrict__ Vh,
    float* __restrict__ agg, float* __restrict__ psum, float* __restrict__ psumsq,
    const float* __restrict__ scale_e, const float* __restrict__ shift_e,
    float* __restrict__ e_out) {
  const int tid = threadIdx.x;
  const int blk = blockIdx.x;
  const int b = blk / N_;
  const int lane = tid & 63, wz = tid >> 6;
  const int c = lane & 15, q = lane >> 4;

  __shared__ __align__(16) unsigned short Bs[128 * 136];  // Cw bf16 [n][k]
  __shared__ float base_s[128];
  __shared__ float ss_s[256];

  const uint4v* bsrc = (const uint4v*)Cwbf;
#pragma unroll
  for (int k2 = 0; k2 < 8; k2++) {
    int g = k2 * 256 + tid;
    int row = g >> 4, col = (g & 15) * 8;
    *(uint4v*)&Bs[row * 136 + col] = bsrc[g];
  }
  if (tid < 128) {
    base_s[tid] = Cb[tid] + Bh[(size_t)blk * D_ + tid];
    if (MODE == 1) { ss_s[tid] = scale_e[tid]; ss_s[128 + tid] = shift_e[tid]; }
  }
  __syncthreads();   // the ONLY barrier before the K-loop

  const float* erow = e + (size_t)blk * N_ * D_;
  const float* AhB = Ah + (size_t)b * N_ * D_;
  const float* VhB = (MODE == 0) ? (Vh + (size_t)b * N_ * D_) : nullptr;

  float aggv[8], sumv[8], sqv[8];
  if (MODE == 0) {
#pragma unroll
    for (int t = 0; t < 8; t++) { aggv[t] = 0.f; sumv[t] = 0.f; sqv[t] = 0.f; }
  }

  float4v ef[8];
  {
    const int j = wz * 16 + c;
    const float* p = erow + (size_t)j * D_ + q * 8;
    const bool ok = (j < N_);
#pragma unroll
    for (int l = 0; l < 4; l++) {
      ef[2 * l]     = ok ? *(const float4v*)(p + l * 32)     : (float4v){0.f,0.f,0.f,0.f};
      ef[2 * l + 1] = ok ? *(const float4v*)(p + l * 32 + 4) : (float4v){0.f,0.f,0.f,0.f};
    }
  }

#pragma unroll
  for (int jt = 0; jt < 4; jt++) {
    const int j0 = jt * 64;
    // convert current tile fragments fp32->bf16
    short8v av[4];
#pragma unroll
    for (int l = 0; l < 4; l++) {
      float4v v0 = ef[2 * l], v1 = ef[2 * l + 1];
      short8v s;
      s[0] = (short)f2b(v0.x); s[1] = (short)f2b(v0.y);
      s[2] = (short)f2b(v0.z); s[3] = (short)f2b(v0.w);
      s[4] = (short)f2b(v1.x); s[5] = (short)f2b(v1.y);
      s[6] = (short)f2b(v1.z); s[7] = (short)f2b(v1.w);
      av[l] = s;
    }
    // prefetch next tile while this tile computes
    if (jt < 3) {
      const int j = (jt + 1) * 64 + wz * 16 + c;
      const float* p = erow + (size_t)j * D_ + q * 8;
      const bool ok = (j < N_);
#pragma unroll
      for (int l = 0; l < 4; l++) {
        ef[2 * l]     = ok ? *(const float4v*)(p + l * 32)     : (float4v){0.f,0.f,0.f,0.f};
        ef[2 * l + 1] = ok ? *(const float4v*)(p + l * 32 + 4) : (float4v){0.f,0.f,0.f,0.f};
      }
    }

    float4v acc[8];
#pragma unroll
    for (int t = 0; t < 8; t++) acc[t] = (float4v){0.f, 0.f, 0.f, 0.f};
#pragma unroll
    for (int t = 0; t < 8; t++) {
      const unsigned short* brow = &Bs[(t * 16 + c) * 136 + q * 8];
#pragma unroll
      for (int l = 0; l < 4; l++) {
        short8v cw = *(const short8v*)(brow + l * 32);
        if (MODE == 0)
          acc[t] = __builtin_amdgcn_mfma_f32_16x16x32_bf16(av[l], cw, acc[t], 0, 0, 0);
        else
          acc[t] = __builtin_amdgcn_mfma_f32_16x16x32_bf16(cw, av[l], acc[t], 0, 0, 0);
      }
    }

    if (MODE == 0) {
      // D layout: n = t*16+c, j = j0 + wz*16 + q*4 + r
#pragma unroll
      for (int t = 0; t < 8; t++) {
        const int n = t * 16 + c;
        const float bse = base_s[n];
#pragma unroll
        for (int r = 0; r < 4; r++) {
          const int j = j0 + wz * 16 + q * 4 + r;
          if (j < N_) {
            float x = acc[t][r] + bse + AhB[(size_t)j * D_ + n];
            float g = __builtin_amdgcn_rcpf(1.0f + __expf(-x));
            aggv[t] += g * VhB[(size_t)j * D_ + n];
            sumv[t] += x;
            sqv[t] += x * x;
          }
        }
      }
    } else {
      // D layout: j = j0 + wz*16 + c (fixed), n = t*16 + q*4 + r  -> float4
      const int j = j0 + wz * 16 + c;
      if (j < N_) {
        const size_t rowoff = (size_t)blk * N_ * D_ + (size_t)j * D_;
#pragma unroll
        for (int t = 0; t < 8; t++) {
          const int n4 = t * 16 + q * 4;
          float4v ah = *(const float4v*)(AhB + (size_t)j * D_ + n4);
          float4v bs4 = *(const float4v*)&base_s[n4];
          float4v sc4 = *(const float4v*)&ss_s[n4];
          float4v sh4 = *(const float4v*)&ss_s[128 + n4];
          float4v ein = *(const float4v*)(e + rowoff + n4);
          float4v o;
#pragma unroll
          for (int r = 0; r < 4; r++) {
            float x = acc[t][r] + bs4[r] + ah[r];
            float y = fmaxf(x * sc4[r] + sh4[r], 0.f);
            o[r] = ein[r] + y;
          }
          *(float4v*)(e_out + rowoff + n4) = o;
        }
      }
    }
  }

  if (MODE == 0) {
    __syncthreads();                 // all MFMA reads of Bs done; reuse as f32
    float* red = (float*)Bs;         // [3][4][128]
#pragma unroll
    for (int t = 0; t < 8; t++) {
      float a = aggv[t], s = sumv[t], sq2 = sqv[t];
      a += __shfl_xor(a, 16); a += __shfl_xor(a, 32);
      s += __shfl_xor(s, 16); s += __shfl_xor(s, 32);
      sq2 += __shfl_xor(sq2, 16); sq2 += __shfl_xor(sq2, 32);
      if (q == 0) {
        red[(0 * 4 + wz) * 128 + t * 16 + c] = a;
        red[(1 * 4 + wz) * 128 + t * 16 + c] = s;
        red[(2 * 4 + wz) * 128 + t * 16 + c] = sq2;
      }
    }
    __syncthreads();
    if (tid < 128) {
      float a = 0.f, s = 0.f, sq2 = 0.f;
#pragma unroll
      for (int w = 0; w < 4; w++) {
        a += red[(0 * 4 + w) * 128 + tid];
        s += red[(1 * 4 + w) * 128 + tid];
        sq2 += red[(2 * 4 + w) * 128 + tid];
      }
      agg[(size_t)blk * D_ + tid] = a;
      psum[(size_t)blk * D_ + tid] = s;
      psumsq[(size_t)blk * D_ + tid] = sq2;
    }
  }
}

// ---------------------------------------------------------------------------
// K2a: coalesced partial reduction of BN stats (100 blocks x 16 rows)
// ---------------------------------------------------------------------------
__global__ __launch_bounds__(256) void stats_part(
    const float* __restrict__ psum, const float* __restrict__ psumsq,
    const float* __restrict__ Uh, const float* __restrict__ agg,
    float* __restrict__ partial) {
  const int t = threadIdx.x, blk = blockIdx.x;
  const int cg = t & 31, rs = t >> 5;
  float4v ps = {0,0,0,0}, pq = {0,0,0,0}, hs = {0,0,0,0}, hq = {0,0,0,0};
#pragma unroll
  for (int p = 0; p < 2; p++) {
    const int row = blk * 16 + p * 8 + rs;
    const size_t off = (size_t)row * D_ + cg * 4;
    float4v a = *(const float4v*)(psum + off);
    float4v bq = *(const float4v*)(psumsq + off);
    float4v u = *(const float4v*)(Uh + off);
    float4v g = *(const float4v*)(agg + off);
    ps += a; pq += bq;
    float4v hv = u + g;
    hs += hv; hq += hv * hv;
  }
  __shared__ float4v red[4][8][32];
  red[0][rs][cg] = ps; red[1][rs][cg] = pq; red[2][rs][cg] = hs; red[3][rs][cg] = hq;
  __syncthreads();
  if (t < 128) {
    const int s = t >> 5, g = t & 31;
    float4v acc = red[s][0][g];
#pragma unroll
    for (int r = 1; r < 8; r++) acc += red[s][r][g];
    *(float4v*)(partial + (size_t)blk * 512 + s * 128 + g * 4) = acc;
  }
}

// ---------------------------------------------------------------------------
// K2b: final stats -> scale/shift (1 block, 128 threads)
// ---------------------------------------------------------------------------
__global__ __launch_bounds__(128) void stats_final(
    const float* __restrict__ partial,
    const float* __restrict__ gamma_h, const float* __restrict__ beta_h,
    const float* __restrict__ gamma_e, const float* __restrict__ beta_e,
    float* __restrict__ scale_e, float* __restrict__ shift_e,
    float* __restrict__ scale_h, float* __restrict__ shift_h) {
  const int n = threadIdx.x;
  float s = 0.f, sq = 0.f, hs = 0.f, hq = 0.f;
  for (int p = 0; p < 100; p++) {
    const float* base = partial + (size_t)p * 512;
    s += base[n]; sq += base[128 + n]; hs += base[256 + n]; hq += base[384 + n];
  }
  const float Me = 8.f * 200.f * 200.f;
  float mean = s / Me;
  float var = sq / Me - mean * mean;
  float sce = gamma_e[n] * rsqrtf(var + 1e-5f);
  scale_e[n] = sce; shift_e[n] = beta_e[n] - mean * sce;
  const float Mh = (float)BN_;
  float mh = hs / Mh;
  float vh = hq / Mh - mh * mh;
  float sch = gamma_h[n] * rsqrtf(vh + 1e-5f);
  scale_h[n] = sch; shift_h[n] = beta_h[n] - mh * sch;
}

// ---------------------------------------------------------------------------
// K3: h_out = h + relu((Uh+agg)*scale_h + shift_h)
// ---------------------------------------------------------------------------
__global__ __launch_bounds__(256) void hpath_kernel(
    const float* __restrict__ h, const float* __restrict__ Uh,
    const float* __restrict__ agg, const float* __restrict__ scale_h,
    const float* __restrict__ shift_h, float* __restrict__ h_out) {
  const int idx = blockIdx.x * 256 + threadIdx.x;
  float4v u = ((const float4v*)Uh)[idx];
  float4v a = ((const float4v*)agg)[idx];
  float4v hv = ((const float4v*)h)[idx];
  float4v sc = ((const float4v*)scale_h)[idx & 31];
  float4v sh = ((const float4v*)shift_h)[idx & 31];
  float4v o;
#pragma unroll
  for (int l = 0; l < 4; l++) {
    float y = fmaxf((u[l] + a[l]) * sc[l] + sh[l], 0.f);
    o[l] = hv[l] + y;
  }
  ((float4v*)h_out)[idx] = o;
}

// ---------------------------------------------------------------------------
extern "C" void kernel_launch(void* const* d_in, const int* in_sizes, int n_in,
                              void* d_out, int out_size, void* d_ws, size_t ws_size,
                              hipStream_t stream) {
  const float* h  = (const float*)d_in[0];
  const float* e  = (const float*)d_in[1];
  const float* Uw = (const float*)d_in[2];  const float* Ub = (const float*)d_in[3];
  const float* Vw = (const float*)d_in[4];  const float* Vb = (const float*)d_in[5];
  const float* Aw = (const float*)d_in[6];  const float* Ab = (const float*)d_in[7];
  const float* Bw = (const float*)d_in[8];  const float* Bb = (const float*)d_in[9];
  const float* Cw = (const float*)d_in[10]; const float* Cb = (const float*)d_in[11];
  const float* gamma_h = (const float*)d_in[12]; const float* beta_h = (const float*)d_in[13];
  const float* gamma_e = (const float*)d_in[14]; const float* beta_e = (const float*)d_in[15];

  float* ws = (float*)d_ws;
  float* Uh = ws + 0;
  float* Vh = ws + (size_t)HN_;
  float* Ah = ws + (size_t)HN_ * 2;
  float* Bh = ws + (size_t)HN_ * 3;
  float* agg = ws + (size_t)HN_ * 4;
  float* psum = ws + (size_t)HN_ * 5;
  float* psumsq = ws + (size_t)HN_ * 6;
  float* scale_e = ws + (size_t)HN_ * 7;
  float* shift_e = scale_e + 128;
  float* scale_h = scale_e + 256;
  float* shift_h = scale_e + 384;
  unsigned short* Cwbf = (unsigned short*)(scale_e + 512);
  float* partial = scale_e + 512 + 8192;   // 100*512 floats

  float* h_out = (float*)d_out;
  float* e_out = (float*)d_out + HN_;

  prelin_kernel<<<116, 256, 0, stream>>>(h, Uw, Ub, Vw, Vb, Aw, Ab, Bw, Bb, Cw,
                                         Uh, Vh, Ah, Bh, Cwbf);
  gemm_pass<0><<<BN_, 256, 0, stream>>>(e, Cwbf, Cb, Ah, Bh, Vh,
                                        agg, psum, psumsq,
                                        nullptr, nullptr, nullptr);
  stats_part<<<100, 256, 0, stream>>>(psum, psumsq, Uh, agg, partial);
  stats_final<<<1, 128, 0, stream>>>(partial, gamma_h, beta_h, gamma_e, beta_e,
                                     scale_e, shift_e, scale_h, shift_h);
  hpath_kernel<<<200, 256, 0, stream>>>(h, Uh, agg, scale_h, shift_h, h_out);
  gemm_pass<1><<<BN_, 256, 0, stream>>>(e, Cwbf, Cb, Ah, Bh, nullptr,
                                        nullptr, nullptr, nullptr,
                                        scale_e, shift_e, e_out);
}